// Round 9
// baseline (507.401 us; speedup 1.0000x reference)
//
#include <hip/hip_runtime.h>

#define HH 512
#define WW 1024
#define NC 19
#define HWP (HH * WW)
#define NB 4
#define NREP 4
#define NXCD 8
#define IGNORE_IDX 255
#define RPAD 4
#define PROWS (2 * RPAD + 1)   // 9 staged rows

typedef float f2v __attribute__((ext_vector_type(2)));
typedef float f4v __attribute__((ext_vector_type(4)));

__device__ __forceinline__ unsigned pack_h2(float a, float b) {
    unsigned short lo = __builtin_bit_cast(unsigned short, (_Float16)a);
    unsigned short hi = __builtin_bit_cast(unsigned short, (_Float16)b);
    return (unsigned)lo | ((unsigned)hi << 16);
}
__device__ __forceinline__ float unpack_h2(unsigned v, int hi) {
    unsigned short u = (unsigned short)(hi ? (v >> 16) : (v & 0xffff));
    return (float)__builtin_bit_cast(_Float16, u);
}

// Block = one image row (1024 px), 256 threads x 4 px (strided by 256 for
// dense coalescing). Channel-major: stage 9-row source patch in LDS
// (coalesced), gather from LDS, pack exp() fp16 in registers.
// ws layout: float acc[NREP][NB][NC][2]
__global__ __launch_bounds__(256) void tc_main(
    const float* __restrict__ preds,
    const float* __restrict__ targets,
    const float* __restrict__ flow,
    const int* __restrict__ labels,
    float* __restrict__ acc)
{
    __shared__ float patch[PROWS * WW];   // 36 KB
    __shared__ float red[4][NC][2];

    const int tid = threadIdx.x;

    // XCD-chunked swizzle: consecutive rows on one XCD -> staged halo rows
    // (each image row is re-staged by 9 row-blocks) hit that XCD's L2.
    const int nwg   = gridDim.x;            // 2048
    const int chunk = nwg / NXCD;           // 256
    const int phys  = blockIdx.x;
    const int logical = (phys % NXCD) * chunk + phys / NXCD;

    const int b = logical >> 9;             // 512 rows per image
    const int y = logical & (HH - 1);

    const float* tb = targets + (size_t)b * NC * HWP;
    const float* pb = preds   + (size_t)b * NC * HWP;
    const f2v*   fb = (const f2v*)(flow + (size_t)b * HWP * 2);
    const int*   lb = labels  + (size_t)b * HWP;

    // ---- Phase A: warp targets for this thread's 4 pixels ----
    int   sp[4];     // clipped global source pixel (fallback path)
    int   slot[4];   // LDS patch offset
    bool  ok[4];     // source row within staged window
    float vf[4];     // valid ? 1 : 0
#pragma unroll
    for (int j = 0; j < 4; ++j) {
        const int x   = tid + j * 256;
        const int pix = y * WW + x;
        const f2v f = __builtin_nontemporal_load(&fb[pix]);
        const int rx = (int)rintf((float)x + f.x);   // half-even == jnp.round
        const int ry = (int)rintf((float)y + f.y);
        const bool valid = (rx >= 0) && (rx < WW) && (ry >= 0) && (ry < HH);
        const int rxc = min(max(rx, 0), WW - 1);
        const int ryc = min(max(ry, 0), HH - 1);
        sp[j] = ryc * WW + rxc;
        const int sl = ryc - (y - RPAD);
        ok[j]   = (sl >= 0) && (sl < PROWS);
        slot[j] = min(max(sl, 0), PROWS - 1) * WW + rxc;
        vf[j]   = valid ? 1.f : 0.f;
    }

    // ---- Phase B: channel-major staged gather + exp -> fp16 pairs in regs ----
    float    psum[4] = {0.f, 0.f, 0.f, 0.f};
    unsigned pe2[NC][2];
#pragma unroll
    for (int c = 0; c < NC; ++c) {
        const float* pc = pb + (size_t)c * HWP;
        __syncthreads();   // previous channel's patch reads complete
#pragma unroll
        for (int i = 0; i < PROWS; ++i) {
            const int r = min(max(y - RPAD + i, 0), HH - 1);
            const f4v v = *(const f4v*)(pc + (size_t)r * WW + 4 * tid);
            *(f4v*)&patch[i * WW + 4 * tid] = v;
        }
        __syncthreads();

        float e4[4];
#pragma unroll
        for (int j = 0; j < 4; ++j) {
            float raw = patch[slot[j]];
            if (!ok[j]) raw = pc[sp[j]];   // rare: |dy| > 4.5 (execz-skipped)
            e4[j] = __expf(raw);
            psum[j] += e4[j];
        }
        pe2[c][0] = pack_h2(e4[0], e4[1]);
        pe2[c][1] = pack_h2(e4[2], e4[3]);
    }
    float pinv[4];
#pragma unroll
    for (int j = 0; j < 4; ++j) pinv[j] = vf[j] / psum[j];

    // ---- Phase C: targets softmax (streaming) + fuzzy IoU ----
    float accn[NC], accd[NC];
#pragma unroll
    for (int c = 0; c < NC; ++c) { accn[c] = 0.f; accd[c] = 0.f; }

#pragma unroll
    for (int j = 0; j < 4; ++j) {
        const int pix = y * WW + tid + j * 256;
        const bool keep = (__builtin_nontemporal_load(&lb[pix]) != IGNORE_IDX);

        float te[NC];
        float tsum = 0.f;
#pragma unroll
        for (int c = 0; c < NC; ++c) {
            te[c] = __expf(__builtin_nontemporal_load(&tb[(size_t)c * HWP + pix]));
            tsum += te[c];
        }
        const float tinv = keep ? (1.0f / tsum) : 0.0f;
        const float pv   = pinv[j];

#pragma unroll
        for (int c = 0; c < NC; ++c) {
            const float t = te[c] * tinv;
            const float p = unpack_h2(pe2[c][j >> 1], j & 1) * pv;
            const float pt = p * t;
            accn[c] += pt;
            accd[c] += p + t - pt;
        }
    }

    // ---- reduction: wave shuffle -> LDS -> one atomic per value ----
#pragma unroll
    for (int c = 0; c < NC; ++c) {
        for (int off = 32; off > 0; off >>= 1) {
            accn[c] += __shfl_xor(accn[c], off);
            accd[c] += __shfl_xor(accd[c], off);
        }
    }
    const int wave = tid >> 6;
    const int lane = tid & 63;
    if (lane == 0) {
#pragma unroll
        for (int c = 0; c < NC; ++c) {
            red[wave][c][0] = accn[c];
            red[wave][c][1] = accd[c];
        }
    }
    __syncthreads();
    if (tid < NC * 2) {
        const int c  = tid >> 1;
        const int wh = tid & 1;
        const float v = red[0][c][wh] + red[1][c][wh] + red[2][c][wh] + red[3][c][wh];
        const int rep = phys & (NREP - 1);
        atomicAdd(&acc[(((size_t)rep * NB + b) * NC + c) * 2 + wh], v);
    }
}

__global__ void tc_final(const float* __restrict__ acc, float* __restrict__ out)
{
    if (threadIdx.x == 0 && blockIdx.x == 0) {
        float total = 0.f;
        for (int b = 0; b < NB; ++b) {
            float m = 0.f;
            for (int c = 0; c < NC; ++c) {
                float n = 0.f, d = 0.f;
                for (int r = 0; r < NREP; ++r) {
                    n += acc[(((size_t)r * NB + b) * NC + c) * 2 + 0];
                    d += acc[(((size_t)r * NB + b) * NC + c) * 2 + 1];
                }
                m += n / d;
            }
            total += 1.0f - m / (float)NC;
        }
        out[0] = total / (float)NB;
    }
}

extern "C" void kernel_launch(void* const* d_in, const int* in_sizes, int n_in,
                              void* d_out, int out_size, void* d_ws, size_t ws_size,
                              hipStream_t stream) {
    const float* preds   = (const float*)d_in[0];
    const float* targets = (const float*)d_in[1];
    const float* flow    = (const float*)d_in[2];
    const int*   labels  = (const int*)d_in[3];
    float* acc = (float*)d_ws;

    hipMemsetAsync(acc, 0, (size_t)NREP * NB * NC * 2 * sizeof(float), stream);

    tc_main<<<2048, 256, 0, stream>>>(preds, targets, flow, labels, acc);
    tc_final<<<1, 64, 0, stream>>>(acc, (float*)d_out);
}

// Round 10
// 136.391 us; speedup vs baseline: 3.7202x; 3.7202x over previous
//
#include <hip/hip_runtime.h>

#define HH 512
#define WW 1024
#define NC 19
#define HWP (HH * WW)
#define NB 4
#define NREP 4
#define NXCD 8
#define IGNORE_IDX 255

typedef float f2v __attribute__((ext_vector_type(2)));
typedef float f4v __attribute__((ext_vector_type(4)));

// R4 structure, but all channel loads are hoisted into registers BEFORE the
// exp/sum stage so ~57 independent loads per thread-iteration are in flight
// at once (R4's VGPR=60 forced a ~10-deep rolling load->exp window; the
// serialized waitcnts were the latency bottleneck).
// 2 px/thread: targets via f2v, flow via f4v, labels via int2.
// ws layout: float acc[NREP][NB][NC][2]
__global__ __launch_bounds__(256) void tc_main(
    const float* __restrict__ preds,
    const float* __restrict__ targets,
    const float* __restrict__ flow,
    const int* __restrict__ labels,
    float* __restrict__ acc)
{
    const int tid = threadIdx.x;

    // XCD-chunked swizzle (R4 win)
    const int nwg   = gridDim.x;            // 2048
    const int chunk = nwg / NXCD;           // 256
    const int phys  = blockIdx.x;
    const int logical = (phys % NXCD) * chunk + phys / NXCD;

    const int blocks_per_img = nwg / NB;    // 512
    const int b   = logical / blocks_per_img;
    const int blk = logical % blocks_per_img;

    const float* tb = targets + (size_t)b * NC * HWP;
    const float* pb = preds   + (size_t)b * NC * HWP;
    const float* fb = flow    + (size_t)b * HWP * 2;
    const int*   lb = labels  + (size_t)b * HWP;

    const int base = blk * 1024;            // one image row

    float accn[NC], accd[NC];
#pragma unroll
    for (int c = 0; c < NC; ++c) { accn[c] = 0.f; accd[c] = 0.f; }

#pragma unroll
    for (int it = 0; it < 2; ++it) {
        const int pix = base + it * 512 + 2 * tid;   // even
        const int y = pix >> 10;
        const int x = pix & (WW - 1);

        const f4v f = *(const f4v*)(fb + (size_t)pix * 2);  // dx0,dy0,dx1,dy1
        const int2 lab = *(const int2*)(lb + pix);

        const int rx0 = (int)rintf((float)x + f.x);        // half-even
        const int ry0 = (int)rintf((float)y + f.y);
        const int rx1 = (int)rintf((float)(x + 1) + f.z);
        const int ry1 = (int)rintf((float)y + f.w);
        const bool v0 = (rx0 >= 0) && (rx0 < WW) && (ry0 >= 0) && (ry0 < HH);
        const bool v1 = (rx1 >= 0) && (rx1 < WW) && (ry1 >= 0) && (ry1 < HH);
        const int sp0 = min(max(ry0, 0), HH - 1) * WW + min(max(rx0, 0), WW - 1);
        const int sp1 = min(max(ry1, 0), HH - 1) * WW + min(max(rx1, 0), WW - 1);

        // ---- load stage: ALL raw values into regs, no dependent math ----
        f2v  traw[NC];
        float praw0[NC], praw1[NC];
#pragma unroll
        for (int c = 0; c < NC; ++c)
            traw[c] = *(const f2v*)(tb + (size_t)c * HWP + pix);
#pragma unroll
        for (int c = 0; c < NC; ++c) {
            const float* pc = pb + (size_t)c * HWP;
            praw0[c] = pc[sp0];
            praw1[c] = pc[sp1];
        }

        // ---- math stage ----
        float ts0 = 0.f, ts1 = 0.f, ps0 = 0.f, ps1 = 0.f;
        float te0[NC], te1[NC], pe0[NC], pe1[NC];
#pragma unroll
        for (int c = 0; c < NC; ++c) {
            te0[c] = __expf(traw[c].x); ts0 += te0[c];
            te1[c] = __expf(traw[c].y); ts1 += te1[c];
            pe0[c] = __expf(praw0[c]);  ps0 += pe0[c];
            pe1[c] = __expf(praw1[c]);  ps1 += pe1[c];
        }
        const float ti0 = (lab.x != IGNORE_IDX) ? (1.0f / ts0) : 0.0f;
        const float ti1 = (lab.y != IGNORE_IDX) ? (1.0f / ts1) : 0.0f;
        const float pi0 = v0 ? (1.0f / ps0) : 0.0f;
        const float pi1 = v1 ? (1.0f / ps1) : 0.0f;

#pragma unroll
        for (int c = 0; c < NC; ++c) {
            const float t0 = te0[c] * ti0;
            const float t1 = te1[c] * ti1;
            const float p0 = pe0[c] * pi0;
            const float p1 = pe1[c] * pi1;
            const float pt0 = p0 * t0;
            const float pt1 = p1 * t1;
            accn[c] += pt0 + pt1;
            accd[c] += (p0 + t0 - pt0) + (p1 + t1 - pt1);
        }
    }

    // ---- reduction: wave shuffle -> LDS -> one atomic per value ----
#pragma unroll
    for (int c = 0; c < NC; ++c) {
        for (int off = 32; off > 0; off >>= 1) {
            accn[c] += __shfl_xor(accn[c], off);
            accd[c] += __shfl_xor(accd[c], off);
        }
    }

    __shared__ float s[4][NC][2];
    const int wave = tid >> 6;
    const int lane = tid & 63;
    if (lane == 0) {
#pragma unroll
        for (int c = 0; c < NC; ++c) {
            s[wave][c][0] = accn[c];
            s[wave][c][1] = accd[c];
        }
    }
    __syncthreads();
    if (tid < NC * 2) {
        const int c = tid >> 1;
        const int which = tid & 1;
        const float v = s[0][c][which] + s[1][c][which] + s[2][c][which] + s[3][c][which];
        const int rep = phys & (NREP - 1);
        atomicAdd(&acc[(((size_t)rep * NB + b) * NC + c) * 2 + which], v);
    }
}

__global__ void tc_final(const float* __restrict__ acc, float* __restrict__ out)
{
    if (threadIdx.x == 0 && blockIdx.x == 0) {
        float total = 0.f;
        for (int b = 0; b < NB; ++b) {
            float m = 0.f;
            for (int c = 0; c < NC; ++c) {
                float n = 0.f, d = 0.f;
                for (int r = 0; r < NREP; ++r) {
                    n += acc[(((size_t)r * NB + b) * NC + c) * 2 + 0];
                    d += acc[(((size_t)r * NB + b) * NC + c) * 2 + 1];
                }
                m += n / d;
            }
            total += 1.0f - m / (float)NC;
        }
        out[0] = total / (float)NB;
    }
}

extern "C" void kernel_launch(void* const* d_in, const int* in_sizes, int n_in,
                              void* d_out, int out_size, void* d_ws, size_t ws_size,
                              hipStream_t stream) {
    const float* preds   = (const float*)d_in[0];
    const float* targets = (const float*)d_in[1];
    const float* flow    = (const float*)d_in[2];
    const int*   labels  = (const int*)d_in[3];
    float* acc = (float*)d_ws;

    hipMemsetAsync(acc, 0, (size_t)NREP * NB * NC * 2 * sizeof(float), stream);

    tc_main<<<2048, 256, 0, stream>>>(preds, targets, flow, labels, acc);
    tc_final<<<1, 64, 0, stream>>>(acc, (float*)d_out);
}